// Round 3
// baseline (1099.225 us; speedup 1.0000x reference)
//
#include <hip/hip_runtime.h>
#include <hip/hip_bf16.h>
#include <cstdint>
#include <cstddef>

#define D 128
#define SBLK 512
#define BNODES 128   // nodes per bucket

typedef __attribute__((ext_vector_type(8))) short short8;
typedef __attribute__((ext_vector_type(4))) float f32x4;

__device__ __forceinline__ unsigned short f2bf(float f) {
    union { float f; unsigned u; } v; v.f = f;
    unsigned r = v.u + 0x7FFF + ((v.u >> 16) & 1);   // RNE
    return (unsigned short)(r >> 16);
}
__device__ __forceinline__ float bflo(unsigned p) {
    union { unsigned u; float f; } v; v.u = p << 16; return v.f;
}
__device__ __forceinline__ float bfhi(unsigned p) {
    union { unsigned u; float f; } v; v.u = p & 0xFFFF0000u; return v.f;
}

// ---- detect whether edge_index arrived as int64 (all hi-dwords zero) ----
__global__ void k_detect(const unsigned* __restrict__ ei, int E, int* flag) {
    if (threadIdx.x == 0 && blockIdx.x == 0) {
        int n = E < 256 ? E : 256;
        int allz = 1;
        for (int k = 0; k < n; ++k) {
            if (ei[2 * k + 1] != 0u) { allz = 0; break; }
        }
        *flag = allz;
    }
}

// ---- W (f32 [D][D]) -> bf16, same layout ----
__global__ void k_wcvt(const float* __restrict__ W, unsigned short* __restrict__ Wbf) {
    int i = blockIdx.x * 256 + threadIdx.x;
    if (i < D * D) Wbf[i] = f2bf(W[i]);
}

// ---- GEMM: h[M][128] = x[M][128] @ W^T, bf16 MFMA, h stored bf16 ----
__global__ __launch_bounds__(256) void k_gemm(const float* __restrict__ x,
                                              const unsigned short* __restrict__ Wbf,
                                              unsigned short* __restrict__ h, int M) {
    int wave = threadIdx.x >> 6, lane = threadIdx.x & 63;
    int m0 = blockIdx.x * 64 + wave * 16;
    int lr = lane & 15;       // row-in-tile (A), col-in-tile (B/D)
    int lg = lane >> 4;       // k-group
    f32x4 acc[8];
#pragma unroll
    for (int i = 0; i < 8; ++i) acc[i] = (f32x4){0.f, 0.f, 0.f, 0.f};

    int row = m0 + lr;
    int rowc = row < M ? row : M - 1;
    const float* xr = x + (size_t)rowc * D;

#pragma unroll
    for (int ks = 0; ks < 4; ++ks) {
        int k0 = ks * 32 + lg * 8;
        float4 a0 = *(const float4*)(xr + k0);
        float4 a1 = *(const float4*)(xr + k0 + 4);
        short8 af;
        af[0] = (short)f2bf(a0.x); af[1] = (short)f2bf(a0.y);
        af[2] = (short)f2bf(a0.z); af[3] = (short)f2bf(a0.w);
        af[4] = (short)f2bf(a1.x); af[5] = (short)f2bf(a1.y);
        af[6] = (short)f2bf(a1.z); af[7] = (short)f2bf(a1.w);
#pragma unroll
        for (int nt = 0; nt < 8; ++nt) {
            short8 bf = *(const short8*)(Wbf + (size_t)(nt * 16 + lr) * D + k0);
            acc[nt] = __builtin_amdgcn_mfma_f32_16x16x32_bf16(af, bf, acc[nt], 0, 0, 0);
        }
    }
#pragma unroll
    for (int nt = 0; nt < 8; ++nt) {
#pragma unroll
        for (int r = 0; r < 4; ++r) {
            int rr = m0 + lg * 4 + r;
            if (rr < M) h[(size_t)rr * D + nt * 16 + lr] = f2bf(acc[nt][r]);
        }
    }
}

// ---- bin edges by dst bucket; entry = src | (dstLow<<24); cursor-local writes ----
__global__ __launch_bounds__(256) void k_bin(const int* __restrict__ ei, int E,
                                             const int* __restrict__ flagp,
                                             int* __restrict__ bcur,
                                             unsigned* __restrict__ binned, int C) {
    int f64 = *flagp;
    for (int e = blockIdx.x * blockDim.x + threadIdx.x; e < E; e += gridDim.x * blockDim.x) {
        int s, d;
        if (f64) { s = ei[2 * e]; d = ei[2 * (E + e)]; }
        else     { s = ei[e];     d = ei[E + e]; }
        int b = d >> 7;                       // bucket = dst / 128
        unsigned dl = (unsigned)(d & (BNODES - 1));
        int pos = atomicAdd(&bcur[b], 1);
        if (pos < C) binned[(size_t)b * C + pos] = (unsigned)s | (dl << 24);
    }
}

// ---- scan bucket counts -> bucket edge bases; rowoff[N]=total ----
__global__ void k_bscan(const int* __restrict__ bcnt, int* __restrict__ bbase,
                        int* __restrict__ rowoff, int NB, int N) {
    __shared__ int sh[1024];
    __shared__ int carry;
    int t = threadIdx.x;
    if (t == 0) carry = 0;
    __syncthreads();
    for (int c0 = 0; c0 < NB; c0 += 1024) {
        int i = c0 + t;
        int v = (i < NB) ? bcnt[i] : 0;
        sh[t] = v;
        __syncthreads();
        for (int off = 1; off < 1024; off <<= 1) {
            int a = (t >= off) ? sh[t - off] : 0;
            __syncthreads();
            sh[t] += a;
            __syncthreads();
        }
        if (i < NB) bbase[i] = carry + sh[t] - v;
        __syncthreads();
        if (t == 0) carry += sh[1023];
        __syncthreads();
    }
    if (t == 0) rowoff[N] = carry;
}

// ---- per-bucket: local degree count, scan -> rowoff/dinv, fill csrc ----
__global__ __launch_bounds__(256) void k_fillB(const unsigned* __restrict__ binned, int C,
                                               const int* __restrict__ bcnt,
                                               const int* __restrict__ bbase,
                                               int* __restrict__ rowoff,
                                               float* __restrict__ dinv,
                                               int* __restrict__ csrc, int N) {
    __shared__ int sdeg[BNODES];
    __shared__ int sscan[BNODES];
    __shared__ int scur[BNODES];
    int b = blockIdx.x;
    int t = threadIdx.x;
    int cnt = bcnt[b];
    if (cnt > C) cnt = C;
    int base = bbase[b];
    const unsigned* ent = binned + (size_t)b * C;

    if (t < BNODES) sdeg[t] = 0;
    __syncthreads();
    for (int i = t; i < cnt; i += 256) {
        unsigned e = ent[i];
        atomicAdd(&sdeg[e >> 24], 1);
    }
    __syncthreads();
    if (t < BNODES) sscan[t] = sdeg[t];
    __syncthreads();
#pragma unroll
    for (int off = 1; off < BNODES; off <<= 1) {
        int a = (t >= off && t < BNODES) ? sscan[t - off] : 0;
        __syncthreads();
        if (t < BNODES) sscan[t] += a;
        __syncthreads();
    }
    if (t < BNODES) {
        int loc = sscan[t] - sdeg[t];          // exclusive local offset
        scur[t] = loc;
        int node = b * BNODES + t;
        if (node < N) {
            rowoff[node] = base + loc;
            int dg = sdeg[t];
            dinv[node] = dg > 0 ? rsqrtf((float)dg) : 0.0f;
        }
    }
    __syncthreads();
    for (int i = t; i < cnt; i += 256) {
        unsigned e = ent[i];
        int pos = atomicAdd(&scur[e >> 24], 1);
        csrc[base + pos] = (int)(e & 0xFFFFFFu);
    }
}

// ---- aggregation: 1 wave per node; lane owns 2 cols (bf16x2 dword) ----
__global__ __launch_bounds__(256) void k_agg(const unsigned* __restrict__ h,
                                             const int* __restrict__ csrc,
                                             const int* __restrict__ rowoff,
                                             const float* __restrict__ dinv,
                                             float2* __restrict__ out, int N) {
    int wave = threadIdx.x >> 6, lane = threadIdx.x & 63;
    int node = blockIdx.x * 4 + wave;
    if (node >= N) return;
    int beg = rowoff[node], end = rowoff[node + 1];
    float ax = 0.f, ay = 0.f;
    int i = beg;
    for (; i + 8 <= end; i += 8) {
        int s0 = csrc[i], s1 = csrc[i + 1], s2 = csrc[i + 2], s3 = csrc[i + 3];
        int s4 = csrc[i + 4], s5 = csrc[i + 5], s6 = csrc[i + 6], s7 = csrc[i + 7];
        unsigned p0 = h[(size_t)s0 * 64 + lane];
        unsigned p1 = h[(size_t)s1 * 64 + lane];
        unsigned p2 = h[(size_t)s2 * 64 + lane];
        unsigned p3 = h[(size_t)s3 * 64 + lane];
        unsigned p4 = h[(size_t)s4 * 64 + lane];
        unsigned p5 = h[(size_t)s5 * 64 + lane];
        unsigned p6 = h[(size_t)s6 * 64 + lane];
        unsigned p7 = h[(size_t)s7 * 64 + lane];
        float w0 = dinv[s0], w1 = dinv[s1], w2 = dinv[s2], w3 = dinv[s3];
        float w4 = dinv[s4], w5 = dinv[s5], w6 = dinv[s6], w7 = dinv[s7];
        ax += w0 * bflo(p0); ay += w0 * bfhi(p0);
        ax += w1 * bflo(p1); ay += w1 * bfhi(p1);
        ax += w2 * bflo(p2); ay += w2 * bfhi(p2);
        ax += w3 * bflo(p3); ay += w3 * bfhi(p3);
        ax += w4 * bflo(p4); ay += w4 * bfhi(p4);
        ax += w5 * bflo(p5); ay += w5 * bfhi(p5);
        ax += w6 * bflo(p6); ay += w6 * bfhi(p6);
        ax += w7 * bflo(p7); ay += w7 * bfhi(p7);
    }
    for (; i < end; ++i) {
        int s = csrc[i];
        float w = dinv[s];
        unsigned p = h[(size_t)s * 64 + lane];
        ax += w * bflo(p); ay += w * bfhi(p);
    }
    float sd = dinv[node];
    out[(size_t)node * 64 + lane] = make_float2(ax * sd, ay * sd);
}

// ---- BN stats: block partials (sum, sumsq) per column ----
__global__ __launch_bounds__(256) void k_stats(const float* __restrict__ agg,
                                               float* __restrict__ part, int N) {
    int t = threadIdx.x;
    int c = t & 127, half = t >> 7;
    float s = 0.f, q = 0.f;
    for (int r = blockIdx.x * 2 + half; r < N; r += SBLK * 2) {
        float v = agg[(size_t)r * 128 + c];
        s += v; q += v * v;
    }
    __shared__ float sh[512];
    sh[t] = s; sh[256 + t] = q;
    __syncthreads();
    if (t < 128) {
        part[blockIdx.x * 256 + t]       = sh[t] + sh[t + 128];
        part[blockIdx.x * 256 + 128 + t] = sh[256 + t] + sh[256 + t + 128];
    }
}

__global__ void k_params(const float* __restrict__ part, const float* __restrict__ gamma,
                         const float* __restrict__ beta, float* __restrict__ params, int N) {
    int t = threadIdx.x;   // 256
    float a = 0.f;
    for (int b = 0; b < SBLK; ++b) a += part[b * 256 + t];
    __shared__ float sh[256];
    sh[t] = a;
    __syncthreads();
    if (t < 128) {
        float mean = sh[t] / (float)N;
        float var = sh[128 + t] / (float)N - mean * mean;
        var = var > 0.f ? var : 0.f;
        float sc = gamma[t] * rsqrtf(var + 1e-5f);
        params[t] = sc;
        params[128 + t] = beta[t] - mean * sc;
    }
}

// ---- finalize in-place: out = relu(agg*scale+shift) + x ----
__global__ __launch_bounds__(256) void k_final(float4* __restrict__ out,
                                               const float4* __restrict__ x,
                                               const float* __restrict__ params, int n4) {
    const float4* p4 = (const float4*)params;
    for (int i = blockIdx.x * 256 + threadIdx.x; i < n4; i += gridDim.x * 256) {
        int c = i & 31;
        float4 s = p4[c], b = p4[32 + c];
        float4 v = out[i], xv = x[i];
        float4 r;
        r.x = fmaxf(v.x * s.x + b.x, 0.f) + xv.x;
        r.y = fmaxf(v.y * s.y + b.y, 0.f) + xv.y;
        r.z = fmaxf(v.z * s.z + b.z, 0.f) + xv.z;
        r.w = fmaxf(v.w * s.w + b.w, 0.f) + xv.w;
        out[i] = r;
    }
}

extern "C" void kernel_launch(void* const* d_in, const int* in_sizes, int n_in,
                              void* d_out, int out_size, void* d_ws, size_t ws_size,
                              hipStream_t stream) {
    const float* x     = (const float*)d_in[0];
    const int*   ei    = (const int*)d_in[1];
    const float* W     = (const float*)d_in[2];
    const float* gamma = (const float*)d_in[3];
    const float* beta  = (const float*)d_in[4];

    int N = in_sizes[0] / D;
    int E = in_sizes[1] / 2;
    int NB = (N + BNODES - 1) / BNODES;
    int EperB = (E + NB - 1) / NB;
    int C = ((EperB + 1024 + 63) / 64) * 64;   // capacity with ~+16 sigma headroom

    char* ws = (char*)d_ws;
    size_t off = 0;
    auto alloc = [&](size_t bytes) { size_t o = off; off = (off + bytes + 255) & ~(size_t)255; return o; };

    unsigned short* h    = (unsigned short*)(ws + alloc((size_t)N * D * 2));
    int*      csrc   = (int*)     (ws + alloc((size_t)E * 4));
    unsigned* binned = (unsigned*)(ws + alloc((size_t)NB * C * 4));
    int*      bcur   = (int*)     (ws + alloc((size_t)NB * 4));
    int*      bbase  = (int*)     (ws + alloc((size_t)NB * 4));
    float*    dinv   = (float*)   (ws + alloc((size_t)N * 4));
    int*      rowoff = (int*)     (ws + alloc((size_t)(N + 1) * 4));
    float*    part   = (float*)   (ws + alloc((size_t)SBLK * 256 * 4));
    float*    params = (float*)   (ws + alloc(256 * 4));
    int*      flagp  = (int*)     (ws + alloc(4));
    unsigned short* Wbf = (unsigned short*)(ws + alloc((size_t)D * D * 2));

    float* outf = (float*)d_out;

    hipMemsetAsync(bcur, 0, (size_t)NB * 4, stream);
    k_detect<<<1, 64, 0, stream>>>((const unsigned*)ei, E, flagp);
    k_wcvt<<<(D * D + 255) / 256, 256, 0, stream>>>(W, Wbf);
    k_gemm<<<(N + 63) / 64, 256, 0, stream>>>(x, Wbf, h, N);
    k_bin<<<2048, 256, 0, stream>>>(ei, E, flagp, bcur, binned, C);
    k_bscan<<<1, 1024, 0, stream>>>(bcur, bbase, rowoff, NB, N);
    k_fillB<<<NB, 256, 0, stream>>>(binned, C, bcur, bbase, rowoff, dinv, csrc, N);
    k_agg<<<(N + 3) / 4, 256, 0, stream>>>((const unsigned*)h, csrc, rowoff, dinv,
                                           (float2*)d_out, N);
    k_stats<<<SBLK, 256, 0, stream>>>(outf, part, N);
    k_params<<<1, 256, 0, stream>>>(part, gamma, beta, params, N);
    k_final<<<2048, 256, 0, stream>>>((float4*)d_out, (const float4*)x, params,
                                      (N * D) / 4);
}

// Round 4
// 396.854 us; speedup vs baseline: 2.7698x; 2.7698x over previous
//
#include <hip/hip_runtime.h>
#include <hip/hip_bf16.h>
#include <cstdint>
#include <cstddef>

#define D 128
#define SBLK 512
#define SBBITS 10                 // 1024 nodes per super-bucket
#define NSB 128                   // max super-buckets (100000>>10 = 97)
#define TILE 2048                 // edges per k_bin block

typedef __attribute__((ext_vector_type(8))) short short8;
typedef __attribute__((ext_vector_type(4))) float f32x4;

__device__ __forceinline__ unsigned short f2bf(float f) {
    union { float f; unsigned u; } v; v.f = f;
    unsigned r = v.u + 0x7FFF + ((v.u >> 16) & 1);   // RNE
    return (unsigned short)(r >> 16);
}
__device__ __forceinline__ float bflo(unsigned p) {
    union { unsigned u; float f; } v; v.u = p << 16; return v.f;
}
__device__ __forceinline__ float bfhi(unsigned p) {
    union { unsigned u; float f; } v; v.u = p & 0xFFFF0000u; return v.f;
}

// ---- detect whether edge_index arrived as int64 (all hi-dwords zero) ----
__global__ void k_detect(const unsigned* __restrict__ ei, int E, int* flag) {
    if (threadIdx.x == 0 && blockIdx.x == 0) {
        int n = E < 256 ? E : 256;
        int allz = 1;
        for (int k = 0; k < n; ++k) {
            if (ei[2 * k + 1] != 0u) { allz = 0; break; }
        }
        *flag = allz;
    }
}

// ---- W (f32 [D][D]) -> bf16, same layout ----
__global__ void k_wcvt(const float* __restrict__ W, unsigned short* __restrict__ Wbf) {
    int i = blockIdx.x * 256 + threadIdx.x;
    if (i < D * D) Wbf[i] = f2bf(W[i]);
}

// ---- GEMM: h[M][128] = x[M][128] @ W^T, bf16 MFMA, h stored bf16 ----
__global__ __launch_bounds__(256) void k_gemm(const float* __restrict__ x,
                                              const unsigned short* __restrict__ Wbf,
                                              unsigned short* __restrict__ h, int M) {
    int wave = threadIdx.x >> 6, lane = threadIdx.x & 63;
    int m0 = blockIdx.x * 64 + wave * 16;
    int lr = lane & 15;       // row-in-tile (A), col-in-tile (B/D)
    int lg = lane >> 4;       // k-group
    f32x4 acc[8];
#pragma unroll
    for (int i = 0; i < 8; ++i) acc[i] = (f32x4){0.f, 0.f, 0.f, 0.f};

    int row = m0 + lr;
    int rowc = row < M ? row : M - 1;
    const float* xr = x + (size_t)rowc * D;

#pragma unroll
    for (int ks = 0; ks < 4; ++ks) {
        int k0 = ks * 32 + lg * 8;
        float4 a0 = *(const float4*)(xr + k0);
        float4 a1 = *(const float4*)(xr + k0 + 4);
        short8 af;
        af[0] = (short)f2bf(a0.x); af[1] = (short)f2bf(a0.y);
        af[2] = (short)f2bf(a0.z); af[3] = (short)f2bf(a0.w);
        af[4] = (short)f2bf(a1.x); af[5] = (short)f2bf(a1.y);
        af[6] = (short)f2bf(a1.z); af[7] = (short)f2bf(a1.w);
#pragma unroll
        for (int nt = 0; nt < 8; ++nt) {
            short8 bf = *(const short8*)(Wbf + (size_t)(nt * 16 + lr) * D + k0);
            acc[nt] = __builtin_amdgcn_mfma_f32_16x16x32_bf16(af, bf, acc[nt], 0, 0, 0);
        }
    }
#pragma unroll
    for (int nt = 0; nt < 8; ++nt) {
#pragma unroll
        for (int r = 0; r < 4; ++r) {
            int rr = m0 + lg * 4 + r;
            if (rr < M) h[(size_t)rr * D + nt * 16 + lr] = f2bf(acc[nt][r]);
        }
    }
}

// ---- pass 1: tile-local LDS sort into 128 super-buckets, contiguous flush ----
// entry = src | (dstLocal << 17)
__global__ __launch_bounds__(256) void k_bin(const int* __restrict__ ei, int E,
                                             const int* __restrict__ flagp,
                                             int* __restrict__ g_sbcnt,
                                             unsigned* __restrict__ binned, int C2) {
    __shared__ unsigned stage[TILE];
    __shared__ unsigned char ssb[TILE];
    __shared__ int hcnt[NSB], hoff[NSB], lcur[NSB], gbase[NSB];
    int f64 = *flagp;
    int t = threadIdx.x;
    int base = blockIdx.x * TILE;
    int cnt = E - base; if (cnt > TILE) cnt = TILE;

    if (t < NSB) hcnt[t] = 0;
    __syncthreads();

    unsigned ent[8]; int esb[8];
#pragma unroll
    for (int j = 0; j < 8; ++j) {
        int idx = j * 256 + t;
        esb[j] = -1;
        if (idx < cnt) {
            int e = base + idx;
            int s, d;
            if (f64) { s = ei[2 * e]; d = ei[2 * (E + e)]; }
            else     { s = ei[e];     d = ei[E + e]; }
            esb[j] = d >> SBBITS;
            ent[j] = (unsigned)s | ((unsigned)(d & ((1 << SBBITS) - 1)) << 17);
            atomicAdd(&hcnt[esb[j]], 1);
        }
    }
    __syncthreads();
    if (t < NSB) hoff[t] = hcnt[t];
    __syncthreads();
#pragma unroll
    for (int off = 1; off < NSB; off <<= 1) {
        int a = (t < NSB && t >= off) ? hoff[t - off] : 0;
        __syncthreads();
        if (t < NSB) hoff[t] += a;
        __syncthreads();
    }
    if (t < NSB) {
        int ex = hoff[t] - hcnt[t];            // exclusive offset
        lcur[t] = ex;
        hoff[t] = ex;
        gbase[t] = (hcnt[t] > 0) ? atomicAdd(&g_sbcnt[t], hcnt[t]) : 0;
    }
    __syncthreads();
#pragma unroll
    for (int j = 0; j < 8; ++j) {
        if (esb[j] >= 0) {
            int p = atomicAdd(&lcur[esb[j]], 1);
            stage[p] = ent[j];
            ssb[p] = (unsigned char)esb[j];
        }
    }
    __syncthreads();
    for (int i = t; i < cnt; i += 256) {       // lanes write consecutive addrs
        int sb = ssb[i];
        int pos = gbase[sb] + (i - hoff[sb]);
        if (pos < C2) binned[(size_t)sb * C2 + pos] = stage[i];
    }
}

// ---- pass 2: per-super-bucket degree/scan/fill, all within L2-resident window ----
__global__ __launch_bounds__(1024) void k_fill2(const unsigned* __restrict__ binned, int C2,
                                                const int* __restrict__ g_sbcnt,
                                                int2* __restrict__ ronode,
                                                float* __restrict__ dinv,
                                                int* __restrict__ csrc, int N) {
    __shared__ int deg[1024];
    __shared__ int scn[1024];
    __shared__ int cur[1024];
    int b = blockIdx.x, t = threadIdx.x;
    int cnt = g_sbcnt[b]; if (cnt > C2) cnt = C2;
    const unsigned* ent = binned + (size_t)b * C2;

    deg[t] = 0;
    __syncthreads();
    for (int i = t; i < cnt; i += 1024) atomicAdd(&deg[ent[i] >> 17], 1);
    __syncthreads();
    scn[t] = deg[t];
    __syncthreads();
    for (int off = 1; off < 1024; off <<= 1) {
        int a = (t >= off) ? scn[t - off] : 0;
        __syncthreads();
        scn[t] += a;
        __syncthreads();
    }
    int ex = scn[t] - deg[t];
    cur[t] = ex;
    int node = (b << SBBITS) + t;
    if (node < N) {
        ronode[node] = make_int2(b * C2 + ex, deg[t]);
        dinv[node] = deg[t] > 0 ? rsqrtf((float)deg[t]) : 0.0f;
    }
    __syncthreads();
    for (int i = t; i < cnt; i += 1024) {
        unsigned e = ent[i];
        int pos = atomicAdd(&cur[e >> 17], 1);
        csrc[b * C2 + pos] = (int)(e & 0x1FFFF);
    }
}

// ---- aggregation: 1 wave per node; lane owns 2 cols (bf16x2 dword) ----
__global__ __launch_bounds__(256) void k_agg(const unsigned* __restrict__ h,
                                             const int* __restrict__ csrc,
                                             const int2* __restrict__ ronode,
                                             const float* __restrict__ dinv,
                                             float2* __restrict__ out, int N) {
    int wave = threadIdx.x >> 6, lane = threadIdx.x & 63;
    int node = blockIdx.x * 4 + wave;
    if (node >= N) return;
    int2 ro = ronode[node];
    int beg = ro.x, end = ro.x + ro.y;
    float ax = 0.f, ay = 0.f;
    int i = beg;
    for (; i + 8 <= end; i += 8) {
        int s0 = csrc[i], s1 = csrc[i + 1], s2 = csrc[i + 2], s3 = csrc[i + 3];
        int s4 = csrc[i + 4], s5 = csrc[i + 5], s6 = csrc[i + 6], s7 = csrc[i + 7];
        unsigned p0 = h[(size_t)s0 * 64 + lane];
        unsigned p1 = h[(size_t)s1 * 64 + lane];
        unsigned p2 = h[(size_t)s2 * 64 + lane];
        unsigned p3 = h[(size_t)s3 * 64 + lane];
        unsigned p4 = h[(size_t)s4 * 64 + lane];
        unsigned p5 = h[(size_t)s5 * 64 + lane];
        unsigned p6 = h[(size_t)s6 * 64 + lane];
        unsigned p7 = h[(size_t)s7 * 64 + lane];
        float w0 = dinv[s0], w1 = dinv[s1], w2 = dinv[s2], w3 = dinv[s3];
        float w4 = dinv[s4], w5 = dinv[s5], w6 = dinv[s6], w7 = dinv[s7];
        ax += w0 * bflo(p0); ay += w0 * bfhi(p0);
        ax += w1 * bflo(p1); ay += w1 * bfhi(p1);
        ax += w2 * bflo(p2); ay += w2 * bfhi(p2);
        ax += w3 * bflo(p3); ay += w3 * bfhi(p3);
        ax += w4 * bflo(p4); ay += w4 * bfhi(p4);
        ax += w5 * bflo(p5); ay += w5 * bfhi(p5);
        ax += w6 * bflo(p6); ay += w6 * bfhi(p6);
        ax += w7 * bflo(p7); ay += w7 * bfhi(p7);
    }
    for (; i < end; ++i) {
        int s = csrc[i];
        float w = dinv[s];
        unsigned p = h[(size_t)s * 64 + lane];
        ax += w * bflo(p); ay += w * bfhi(p);
    }
    float sd = dinv[node];
    out[(size_t)node * 64 + lane] = make_float2(ax * sd, ay * sd);
}

// ---- BN stats: block partials (sum, sumsq) per column ----
__global__ __launch_bounds__(256) void k_stats(const float* __restrict__ agg,
                                               float* __restrict__ part, int N) {
    int t = threadIdx.x;
    int c = t & 127, half = t >> 7;
    float s = 0.f, q = 0.f;
    for (int r = blockIdx.x * 2 + half; r < N; r += SBLK * 2) {
        float v = agg[(size_t)r * 128 + c];
        s += v; q += v * v;
    }
    __shared__ float sh[512];
    sh[t] = s; sh[256 + t] = q;
    __syncthreads();
    if (t < 128) {
        part[blockIdx.x * 256 + t]       = sh[t] + sh[t + 128];
        part[blockIdx.x * 256 + 128 + t] = sh[256 + t] + sh[256 + t + 128];
    }
}

__global__ void k_params(const float* __restrict__ part, const float* __restrict__ gamma,
                         const float* __restrict__ beta, float* __restrict__ params, int N) {
    int t = threadIdx.x;   // 256
    float a = 0.f;
    for (int b = 0; b < SBLK; ++b) a += part[b * 256 + t];
    __shared__ float sh[256];
    sh[t] = a;
    __syncthreads();
    if (t < 128) {
        float mean = sh[t] / (float)N;
        float var = sh[128 + t] / (float)N - mean * mean;
        var = var > 0.f ? var : 0.f;
        float sc = gamma[t] * rsqrtf(var + 1e-5f);
        params[t] = sc;
        params[128 + t] = beta[t] - mean * sc;
    }
}

// ---- finalize in-place: out = relu(agg*scale+shift) + x ----
__global__ __launch_bounds__(256) void k_final(float4* __restrict__ out,
                                               const float4* __restrict__ x,
                                               const float* __restrict__ params, int n4) {
    const float4* p4 = (const float4*)params;
    for (int i = blockIdx.x * 256 + threadIdx.x; i < n4; i += gridDim.x * 256) {
        int c = i & 31;
        float4 s = p4[c], b = p4[32 + c];
        float4 v = out[i], xv = x[i];
        float4 r;
        r.x = fmaxf(v.x * s.x + b.x, 0.f) + xv.x;
        r.y = fmaxf(v.y * s.y + b.y, 0.f) + xv.y;
        r.z = fmaxf(v.z * s.z + b.z, 0.f) + xv.z;
        r.w = fmaxf(v.w * s.w + b.w, 0.f) + xv.w;
        out[i] = r;
    }
}

extern "C" void kernel_launch(void* const* d_in, const int* in_sizes, int n_in,
                              void* d_out, int out_size, void* d_ws, size_t ws_size,
                              hipStream_t stream) {
    const float* x     = (const float*)d_in[0];
    const int*   ei    = (const int*)d_in[1];
    const float* W     = (const float*)d_in[2];
    const float* gamma = (const float*)d_in[3];
    const float* beta  = (const float*)d_in[4];

    int N = in_sizes[0] / D;
    int E = in_sizes[1] / 2;
    int NSBu = (N + (1 << SBBITS) - 1) >> SBBITS;          // used super-buckets
    int avg = (E + NSBu - 1) / NSBu;
    int C2 = ((avg + 4096 + 63) / 64) * 64;                // ~ +22 sigma headroom

    char* ws = (char*)d_ws;
    size_t off = 0;
    auto alloc = [&](size_t bytes) { size_t o = off; off = (off + bytes + 255) & ~(size_t)255; return o; };

    unsigned short* h    = (unsigned short*)(ws + alloc((size_t)N * D * 2));
    int*      csrc   = (int*)     (ws + alloc((size_t)NSBu * C2 * 4));
    unsigned* binned = (unsigned*)(ws + alloc((size_t)NSBu * C2 * 4));
    int*      g_sbcnt= (int*)     (ws + alloc((size_t)NSB * 4));
    float*    dinv   = (float*)   (ws + alloc((size_t)N * 4));
    int2*     ronode = (int2*)    (ws + alloc((size_t)N * 8));
    float*    part   = (float*)   (ws + alloc((size_t)SBLK * 256 * 4));
    float*    params = (float*)   (ws + alloc(256 * 4));
    int*      flagp  = (int*)     (ws + alloc(4));
    unsigned short* Wbf = (unsigned short*)(ws + alloc((size_t)D * D * 2));

    float* outf = (float*)d_out;

    hipMemsetAsync(g_sbcnt, 0, (size_t)NSB * 4, stream);
    k_detect<<<1, 64, 0, stream>>>((const unsigned*)ei, E, flagp);
    k_wcvt<<<(D * D + 255) / 256, 256, 0, stream>>>(W, Wbf);
    k_gemm<<<(N + 63) / 64, 256, 0, stream>>>(x, Wbf, h, N);
    k_bin<<<(E + TILE - 1) / TILE, 256, 0, stream>>>(ei, E, flagp, g_sbcnt, binned, C2);
    k_fill2<<<NSBu, 1024, 0, stream>>>(binned, C2, g_sbcnt, ronode, dinv, csrc, N);
    k_agg<<<(N + 3) / 4, 256, 0, stream>>>((const unsigned*)h, csrc, ronode, dinv,
                                           (float2*)d_out, N);
    k_stats<<<SBLK, 256, 0, stream>>>(outf, part, N);
    k_params<<<1, 256, 0, stream>>>(part, gamma, beta, params, N);
    k_final<<<2048, 256, 0, stream>>>((float4*)d_out, (const float4*)x, params,
                                      (N * D) / 4);
}